// Round 1
// baseline (127.389 us; speedup 1.0000x reference)
//
#include <hip/hip_runtime.h>

// Problem: out[n,o,j,i] = sum_{a,b} inp[n,2,i+a,j+b] * kt[o,a,b]
//   inp: (32,3,224,224) f32, kt: (64,5,5) f32, out: (32,64,220,220) f32
// Flat f = j*220 + i over the output's last two dims -> store addr = base + f
// (perfect coalescing; the swapaxes is free in this indexing).

#define IMG_HW   224
#define OUT_HW   220
#define FLAT     (OUT_HW * OUT_HW)   // 48400
#define NOUT     64
#define KW       5
#define PITCH    7                    // odd -> conflict-free LDS at lane stride 7
#define SLAB     (IMG_HW * PITCH)     // 224 rows x 7 cols = 1568 floats (6.3 KB)
#define BLOCK    256

__global__ __launch_bounds__(BLOCK, 4)
void ConvolutionalLayer_88742614270062_kernel(const float* __restrict__ inp,
                                              const float* __restrict__ kt,
                                              float* __restrict__ out) {
    __shared__ float s[SLAB];

    const int n  = blockIdx.y;
    const int f0 = blockIdx.x * BLOCK;          // first flat output index
    const int j0 = f0 / OUT_HW;                 // first output column this block touches

    // channel 2 of image n
    const float* __restrict__ xb = inp + ((size_t)(n * 3 + 2)) * (IMG_HW * IMG_HW);

    // Stage slab: all 224 input rows, cols j0 .. j0+6 (block spans <=3 output
    // columns; +4 for the kernel width). Guard the right edge.
    for (int idx = threadIdx.x; idx < SLAB; idx += BLOCK) {
        int r   = idx / PITCH;
        int c   = idx - r * PITCH;
        int col = j0 + c;
        s[idx]  = (col < IMG_HW) ? xb[r * IMG_HW + col] : 0.0f;
    }
    __syncthreads();

    const int f = f0 + (int)threadIdx.x;
    if (f >= FLAT) return;

    const int j  = f / OUT_HW;      // output column (input W index)
    const int i  = f - j * OUT_HW;  // output row    (input H index, innermost)
    const int cj = j - j0;          // 0..2

    // Each lane loads its 5x5 input window once (25 regs), reused by all 64 o.
    float v[KW * KW];
#pragma unroll
    for (int a = 0; a < KW; ++a) {
#pragma unroll
        for (int b = 0; b < KW; ++b) {
            v[a * KW + b] = s[(i + a) * PITCH + cj + b];
        }
    }

    float* __restrict__ op = out + (size_t)n * (NOUT * FLAT) + f;

    // Weights are wave-uniform -> scalar loads; FMA reads them from SGPR.
#pragma unroll 4
    for (int o = 0; o < NOUT; ++o) {
        float acc = 0.0f;
#pragma unroll
        for (int t = 0; t < KW * KW; ++t) {
            acc = fmaf(kt[o * (KW * KW) + t], v[t], acc);
        }
        op[(size_t)o * FLAT] = acc;   // lanes consecutive in f: coalesced
    }
}

extern "C" void kernel_launch(void* const* d_in, const int* in_sizes, int n_in,
                              void* d_out, int out_size, void* d_ws, size_t ws_size,
                              hipStream_t stream) {
    const float* inp = (const float*)d_in[0];   // (32,3,224,224)
    const float* kt  = (const float*)d_in[1];   // (64,5,5)
    float* out       = (float*)d_out;           // (32,64,220,220)

    dim3 grid((FLAT + BLOCK - 1) / BLOCK, 32);  // 190 x 32 blocks
    ConvolutionalLayer_88742614270062_kernel<<<grid, BLOCK, 0, stream>>>(inp, kt, out);
}